// Round 4
// baseline (454.109 us; speedup 1.0000x reference)
//
#include <hip/hip_runtime.h>
#include <stdint.h>

typedef __attribute__((ext_vector_type(8))) short short8;
typedef __attribute__((ext_vector_type(4))) short sh4;
typedef __attribute__((ext_vector_type(4))) float floatx4;
typedef __attribute__((ext_vector_type(4))) unsigned int uintx4;

__device__ __forceinline__ float bs2f(short s) {
  union { unsigned int u; float f; } cv;
  cv.u = ((unsigned int)(unsigned short)s) << 16;
  return cv.f;
}
__device__ __forceinline__ short f2bs(float x) {
  union { float f; unsigned int u; } cv; cv.f = x;
  unsigned int u = cv.u;
  u += 0x7fffu + ((u >> 16) & 1u);   // round-to-nearest-even
  return (short)(u >> 16);
}
// pack two fp32 -> bf16x2 (round-half-up) in 3 VALU: two adds + v_perm
__device__ __forceinline__ unsigned int pack_bf16(float a, float b) {
  unsigned int ua = __float_as_uint(a) + 0x8000u;
  unsigned int ub = __float_as_uint(b) + 0x8000u;
  return __builtin_amdgcn_perm(ub, ua, 0x07060302u);  // [ub.hi16 : ua.hi16]
}
// async global->LDS, 16 bytes per lane (wave-uniform LDS base + lane*16)
__device__ __forceinline__ void async_copy16(const void* g, void* l) {
  __builtin_amdgcn_global_load_lds(
      (const __attribute__((address_space(1))) void*)g,
      (__attribute__((address_space(3))) void*)l, 16, 0, 0);
}

// counted waits / barrier: single asm blocks = compiler memory fence on both
// sides. BAR() == __syncthreads() minus the vmcnt(0) drain (the whole point:
// T4 counted-vmcnt — global_load_lds stays in flight ACROSS barriers).
#define WAIT_VM(N) asm volatile("s_waitcnt vmcnt(" #N ")" ::: "memory")
#define BAR() asm volatile("s_waitcnt lgkmcnt(0)\ns_barrier" ::: "memory")

// ---------------------------------------------------------------------------
// 3-buffer counted-vmcnt GEMM pipeline. Tile 256x128, BK=64, 8 waves (4Mx2N),
// per-wave 64x64 output (4x4 16x16 frags), LDS 144 KB (3 x (A 32K + B 16K)).
// Schedule per K-tile u:  issue stage(u+2) -> compute(u) -> counted vmcnt
// -> [pack A(u+2) if fp32] -> lgkm+barrier.  vmcnt never drains to 0 in the
// main loop; exactly one barrier per K-tile (vs 2 with vm-drain before).
//
// LDS bank swizzle (T2): 16B granule slot = g ^ (row&7). Staged via
// inverse-permuted GLOBAL source for global_load_lds (linear LDS dest, rule
// #21) / swizzled ds_write for the packed-fp32 A path. Fragment reads then
// hit slot (kk/8+lq)^(lm&7): 8 granules x 2 rows each -> 2-way max (free).
//
// Soundness of waits (per-wave vmcnt + barrier for cross-wave):
//  - iter u issues A(u+2) [4 ops] then B(u+2) [2 ops]; WAIT leaves the
//    youngest ops only => tile(u+1)'s B (older) has landed before the
//    barrier that precedes compute(u+1). A-fp32 regs for pack have landed.
//  - buffer (u+2)%3 == (u-1)%3 is written only after this iter's barrier
//    entry, i.e. after ALL waves finished compute(u-1) reads of it.
//  - last tile: explicit vmcnt(0) + barrier (epilogue drain, allowed).
// ---------------------------------------------------------------------------
#define GBM 256
#define GBN 128
#define GBK 64
#define GNT 16   // K / GBK with K=1024

// T1 XCD swizzle: per-z grid 8x64 = 512 blocks (%8==0, bijective; z offset
// 512 preserves blockid%8). XCD x gets m-strips [8x,8x+8) with all 8
// n-blocks adjacent -> A panel reuse stays in one XCD's L2 (r1: 528->98MB).
__device__ __forceinline__ void swizzle_mn_p(int& m0, int& n0) {
  int flat = blockIdx.x + (blockIdx.y << 3);   // gridDim.x == 8
  int swz = (flat & 7) * 64 + (flat >> 3);     // chunk = 512/8 = 64
  n0 = (swz & 7) * GBN;
  m0 = (swz >> 3) * GBM;
}

// AFP32: A is fp32, reg-staged + pack + swizzled ds_write.
// else:  A is bf16 via global_load_lds (pre-swizzled source).
// PBB:   B pointer is per-batch (WPg[b]), b = m0>>11.
template<int AFP32, int OUTF32, int RESID, int PBB>
__global__ __launch_bounds__(512) void gemm_pipe(
    const void* __restrict__ A0, const void* __restrict__ A1,
    const short* __restrict__ B0, const short* __restrict__ B1,
    void* __restrict__ C0, void* __restrict__ C1,
    const short* __restrict__ resid, int N, int K)
{
  __shared__ __align__(16) short As[3][GBM * GBK];   // 3 x 32 KB
  __shared__ __align__(16) short Bs[3][GBN * GBK];   // 3 x 16 KB

  const void*  Avp = blockIdx.z ? A1 : A0;
  const short* Bp  = blockIdx.z ? B1 : B0;
  void*        Cp  = blockIdx.z ? C1 : C0;

  const int tid = threadIdx.x;
  const int wave = tid >> 6, lane = tid & 63;
  const int lm = lane & 15, lq = lane >> 4;
  const int wm = (wave >> 1) * 64;   // 4 M-waves
  const int wn = (wave & 1) * 64;    // 2 N-waves
  int m0, n0;
  swizzle_mn_p(m0, n0);
  if (PBB) Bp += (size_t)(m0 >> 11) * (1024 * 1024);
  const int r8 = tid >> 3, g = tid & 7;   // staging: 8 threads per 128B row

  floatx4 acc[4][4];
#pragma unroll
  for (int r = 0; r < 4; ++r)
#pragma unroll
    for (int c = 0; c < 4; ++c) acc[r][c] = (floatx4)0.0f;

  floatx4 pa[4][2];   // fp32-A in flight (static indexing only)

  auto stageB = [&](int buf, int kb) {   // 2 gload_lds
#pragma unroll
    for (int it = 0; it < 2; ++it) {
      int row = it * 64 + r8;
      async_copy16(&Bp[(size_t)(n0 + row) * K + kb + ((g ^ (row & 7)) << 3)],
                   &Bs[buf][row * GBK + g * 8]);
    }
  };
  auto stageAb = [&](int buf, int kb) {  // bf16 A: 4 gload_lds
    const short* Ab = (const short*)Avp;
#pragma unroll
    for (int it = 0; it < 4; ++it) {
      int row = it * 64 + r8;
      async_copy16(&Ab[(size_t)(m0 + row) * K + kb + ((g ^ (row & 7)) << 3)],
                   &As[buf][row * GBK + g * 8]);
    }
  };
  auto loadA = [&](int kb) {             // fp32 A: 4x2 dwordx4 to regs
    const float* Af = (const float*)Avp;
#pragma unroll
    for (int it = 0; it < 4; ++it) {
      const float* ap = Af + (size_t)(m0 + it * 64 + r8) * K + kb + g * 8;
      pa[it][0] = *reinterpret_cast<const floatx4*>(ap);
      pa[it][1] = *reinterpret_cast<const floatx4*>(ap + 4);
    }
  };
  auto packA = [&](int buf) {            // pack + swizzled ds_write
#pragma unroll
    for (int it = 0; it < 4; ++it) {
      int row = it * 64 + r8;
      int slot = g ^ (row & 7);
      uintx4 av;
      av[0] = pack_bf16(pa[it][0][0], pa[it][0][1]);
      av[1] = pack_bf16(pa[it][0][2], pa[it][0][3]);
      av[2] = pack_bf16(pa[it][1][0], pa[it][1][1]);
      av[3] = pack_bf16(pa[it][1][2], pa[it][1][3]);
      *reinterpret_cast<uintx4*>(&As[buf][row * GBK + slot * 8]) = av;
    }
  };
  auto compute = [&](int buf) {
#pragma unroll
    for (int kk = 0; kk < 2; ++kk) {     // granule base 0 / 4 (k 0 / 32)
      short8 af[4], bfv[4];
      const int slotx = (kk * 4 + lq) ^ (lm & 7);
#pragma unroll
      for (int r = 0; r < 4; ++r)
        af[r] = *reinterpret_cast<const short8*>(
            &As[buf][(wm + r * 16 + lm) * GBK + slotx * 8]);
#pragma unroll
      for (int c = 0; c < 4; ++c)
        bfv[c] = *reinterpret_cast<const short8*>(
            &Bs[buf][(wn + c * 16 + lm) * GBK + slotx * 8]);
#pragma unroll
      for (int r = 0; r < 4; ++r)
#pragma unroll
        for (int c = 0; c < 4; ++c)
          acc[r][c] = __builtin_amdgcn_mfma_f32_16x16x32_bf16(
              af[r], bfv[c], acc[r][c], 0, 0, 0);
    }
  };

  // ---- prologue: tiles 0,1 into bufs 0,1 ----
  if (AFP32) {
    loadA(0); stageB(0, 0);
    WAIT_VM(2);            // A0 regs ready; B0 still allowed in flight
    packA(0);
    loadA(GBK); stageB(1, GBK);
    WAIT_VM(2);            // A1 ready; B0 (older) landed; B1 in flight
    packA(1);
  } else {
    stageAb(0, 0);  stageB(0, 0);
    stageAb(1, GBK); stageB(1, GBK);
    WAIT_VM(6);            // tile0 landed; tile1 in flight
  }
  BAR();

  int cur = 0, stg = 2;
  for (int u = 0; u < GNT - 2; ++u) {
    const int kb = (u + 2) * GBK;
    if (AFP32) {
      loadA(kb);           // 4 vmem (oldest of this iter)
      stageB(stg, kb);     // 2 gload_lds
      compute(cur);
      WAIT_VM(2);          // A(u+2) regs ready; B(u+1) landed; B(u+2) flies
      packA(stg);          // buf(u+2)%3 free: all waves passed prev barrier
    } else {
      stageAb(stg, kb);    // 4 gload_lds
      stageB(stg, kb);     // 2 gload_lds
      compute(cur);
      WAIT_VM(6);          // tile(u+1) landed; tile(u+2) stays in flight
    }
    BAR();                 // lgkm drain (ds_writes visible) + barrier; NO vm drain
    cur = (cur == 2) ? 0 : cur + 1;
    stg = (stg == 2) ? 0 : stg + 1;
  }
  compute(cur);            // tile GNT-2
  WAIT_VM(0);              // final drain: tile GNT-1's B (and A) landed
  BAR();
  cur = (cur == 2) ? 0 : cur + 1;
  compute(cur);            // tile GNT-1

#pragma unroll
  for (int r = 0; r < 4; ++r)
#pragma unroll
    for (int c = 0; c < 4; ++c) {
      int col = n0 + wn + c * 16 + lm;
#pragma unroll
      for (int reg = 0; reg < 4; ++reg) {
        int row = m0 + wm + r * 16 + lq * 4 + reg;  // C/D: col=lane&15
        size_t idx = (size_t)row * N + col;
        float v = acc[r][c][reg];
        if (RESID) v += bs2f(resid[idx]);
        if (OUTF32) ((float*)Cp)[idx] = v;
        else        ((short*)Cp)[idx] = f2bs(v);
      }
    }
}

// out[n][k] = bf16(in[k][n]) for 1024x1024 fp32; blockIdx.z selects matrix
__global__ __launch_bounds__(256) void transpose_cvt3(
    const float* __restrict__ i0, const float* __restrict__ i1,
    const float* __restrict__ i2, short* __restrict__ o0,
    short* __restrict__ o1, short* __restrict__ o2) {
  const float* in = blockIdx.z == 0 ? i0 : (blockIdx.z == 1 ? i1 : i2);
  short* out = blockIdx.z == 0 ? o0 : (blockIdx.z == 1 ? o1 : o2);
  __shared__ short tile[32][33];
  int bx = blockIdx.x * 32, by = blockIdx.y * 32;
  int tx = threadIdx.x & 31;
  int ty = threadIdx.x >> 5;
#pragma unroll
  for (int i = 0; i < 32; i += 8)
    tile[ty + i][tx] = f2bs(in[(size_t)(by + ty + i) * 1024 + bx + tx]);
  __syncthreads();
#pragma unroll
  for (int i = 0; i < 32; i += 8)
    out[(size_t)(bx + ty + i) * 1024 + by + tx] = tile[tx][ty + i];
}

// WaB[e][k] = bf16(Wa[k][e]), same for Wb. grid 128 x 256.
__global__ __launch_bounds__(256) void w_transpose(const float* __restrict__ Wa,
                                                   const float* __restrict__ Wb,
                                                   short* __restrict__ WaB,
                                                   short* __restrict__ WbB) {
  int idx = blockIdx.x * 256 + threadIdx.x;   // 0..32767
  const float* src = idx < 16384 ? Wa : Wb;
  short* dst = idx < 16384 ? WaB : WbB;
  int i = idx & 16383;
  int e = i >> 10, k = i & 1023;
  dst[i] = f2bs(src[k * 16 + e]);
}

// WPg[b][n][k] = bf16( WPT[n][k] * gv[b][k] )  -- gv folded into B side of
// the out-projection (exact diagonal algebra); kills the scale_a round-trip.
__global__ __launch_bounds__(256) void wp_scale(const short* __restrict__ WPT,
                                                const float* __restrict__ gv,
                                                short* __restrict__ WPg) {
  size_t idx = ((size_t)blockIdx.x * 256 + threadIdx.x) * 8;  // over 8M
  int b = (int)(idx >> 20);
  int nk = (int)(idx & 1048575);
  int k = nk & 1023;
  short8 w = *reinterpret_cast<const short8*>(&WPT[nk]);
  const float* gp = gv + b * 1024 + k;
  short8 o;
#pragma unroll
  for (int e = 0; e < 8; ++e) o[e] = f2bs(bs2f(w[e]) * gp[e]);
  *reinterpret_cast<short8*>(&WPg[idx]) = o;
}

// Skinny MFMA GEMM + fused exp: out[(b*16+e)*2048+s] = exp(0.125 * <A,W>).
// Max-subtraction-free softmax: glorot-scaled logits are O(1), fp32 exp safe.
template<int SCRAMBLE>
__global__ __launch_bounds__(64) void skinny_logits(
    const short* __restrict__ X, const short* __restrict__ WB,
    const float* __restrict__ qg, float* __restrict__ out)
{
  const int lane = threadIdx.x;
  const int lm = lane & 15, lq = lane >> 4;
  const int blk = blockIdx.x;           // 0..1023
  const int b = blk >> 7;
  const int s0 = (blk & 127) * 16;      // row offset within batch
  floatx4 acc = (floatx4)0.0f;
  const short* b0 = WB + lm * 1024 + lq * 8;

  if (!SCRAMBLE) {
    const short* a0 = X + ((size_t)(b * 2048 + s0 + lm)) * 1024 + lq * 8;
#pragma unroll 16
    for (int c = 0; c < 32; ++c) {
      short8 a  = *reinterpret_cast<const short8*>(a0 + c * 32);
      short8 bf = *reinterpret_cast<const short8*>(b0 + c * 32);
      acc = __builtin_amdgcn_mfma_f32_16x16x32_bf16(a, bf, acc, 0, 0, 0);
    }
  } else {
    const int h = s0 >> 7, t0 = s0 & 127;
    const float* qgp = qg + b * 1024 + h * 64;
    const short* xb = X + ((size_t)(b * 2048 + (t0 + lm) * 16)) * 1024 + h * 64;
#pragma unroll 16
    for (int c = 0; c < 32; ++c) {
      int dp = c * 32 + lq * 8;         // k index within 1024
      int u = dp >> 6, j0 = dp & 63;    // 8-aligned, never crosses u
      short8 a = *reinterpret_cast<const short8*>(xb + (size_t)u * 1024 + j0);
      floatx4 g0 = *reinterpret_cast<const floatx4*>(qgp + j0);
      floatx4 g1 = *reinterpret_cast<const floatx4*>(qgp + j0 + 4);
      uintx4 av;
      av[0] = pack_bf16(bs2f(a[0]) * g0[0], bs2f(a[1]) * g0[1]);
      av[1] = pack_bf16(bs2f(a[2]) * g0[2], bs2f(a[3]) * g0[3]);
      av[2] = pack_bf16(bs2f(a[4]) * g1[0], bs2f(a[5]) * g1[1]);
      av[3] = pack_bf16(bs2f(a[6]) * g1[2], bs2f(a[7]) * g1[3]);
      short8 as = __builtin_bit_cast(short8, av);
      short8 bf = *reinterpret_cast<const short8*>(b0 + c * 32);
      acc = __builtin_amdgcn_mfma_f32_16x16x32_bf16(as, bf, acc, 0, 0, 0);
    }
  }
  // D: col(e)=lane&15, row=lq*4+reg; rows are consecutive s -> float4 store
  float* o = out + ((size_t)(b * 16 + lm)) * 2048 + s0 + lq * 4;
  floatx4 r;
#pragma unroll
  for (int i = 0; i < 4; ++i) r[i] = __expf(acc[i] * 0.125f);
  *reinterpret_cast<floatx4*>(o) = r;
}

// partial weighted pooling over UNNORMALIZED exp weights:
// grid 512 (b=blk>>6, sc=blk&63), 32 s-rows each.
// part[blk][d] = sum_{s in chunk} ew[b, d>>6, s] * X[b,s,d]
// psum[blk][h] = sum_{s in chunk} ew[b, h, s]
__global__ __launch_bounds__(256) void pool_partial(const float* __restrict__ ew,
                                                    const short* __restrict__ X,
                                                    float* __restrict__ part,
                                                    float* __restrict__ psum) {
  __shared__ float p[16][32];
  int blk = blockIdx.x, b = blk >> 6, sc = blk & 63, s0 = sc * 32;
  int tid = threadIdx.x;
  {
    int h = tid >> 4, ss = (tid & 15) * 2;
    const float* pr = ew + (size_t)(b * 16 + h) * 2048 + s0 + ss;
    p[h][ss] = pr[0]; p[h][ss + 1] = pr[1];
  }
  __syncthreads();
  if (tid < 16) {
    float s = 0.f;
#pragma unroll
    for (int j = 0; j < 32; ++j) s += p[tid][j];
    psum[blk * 16 + tid] = s;
  }
  int d = tid * 4, h = tid >> 4;
  float a0 = 0, a1 = 0, a2 = 0, a3 = 0;
  const short* Xp = X + ((size_t)b * 2048 + s0) * 1024 + d;
#pragma unroll 4
  for (int s = 0; s < 32; ++s) {
    sh4 x = *reinterpret_cast<const sh4*>(Xp + (size_t)s * 1024);
    float w = p[h][s];
    a0 += w * bs2f(x[0]); a1 += w * bs2f(x[1]);
    a2 += w * bs2f(x[2]); a3 += w * bs2f(x[3]);
  }
  float* o = part + (size_t)blk * 1024 + d;
  o[0] = a0; o[1] = a1; o[2] = a2; o[3] = a3;
}

// out[b*1024+d] = (SCALE ? g : 1) * (sum_sc part[..][d]) / (sum_sc psum[..][h])
template<int SCALE>
__global__ __launch_bounds__(256) void pool_reduce(const float* __restrict__ part,
                                                   const float* __restrict__ psum,
                                                   const float* __restrict__ g,
                                                   float* __restrict__ out) {
  int b = blockIdx.x, d = threadIdx.x * 4, h = threadIdx.x >> 4;
  float a0 = 0, a1 = 0, a2 = 0, a3 = 0, hs = 0;
  for (int sc = 0; sc < 64; ++sc) {
    const float* pp = part + (size_t)(b * 64 + sc) * 1024 + d;
    a0 += pp[0]; a1 += pp[1]; a2 += pp[2]; a3 += pp[3];
    hs += psum[(b * 64 + sc) * 16 + h];   // same addr across 16 lanes: broadcast
  }
  float inv = 1.0f / hs;
  a0 *= inv; a1 *= inv; a2 *= inv; a3 *= inv;
  if (SCALE) {
    const float* gp = g + b * 1024 + d;
    a0 *= gp[0]; a1 *= gp[1]; a2 *= gp[2]; a3 *= gp[3];
  }
  float* op = out + b * 1024 + d;
  op[0] = a0; op[1] = a1; op[2] = a2; op[3] = a3;
}

extern "C" void kernel_launch(void* const* d_in, const int* in_sizes, int n_in,
                              void* d_out, int out_size, void* d_ws, size_t ws_size,
                              hipStream_t stream) {
  (void)in_sizes; (void)n_in; (void)out_size; (void)ws_size;
  const float* Qseq = (const float*)d_in[0];
  const float* Kseq = (const float*)d_in[1];
  // d_in[2] = V_seq, unused (faithful to reference)
  const float* WQ = (const float*)d_in[3];
  const float* WK = (const float*)d_in[4];
  const float* Wa = (const float*)d_in[5];
  const float* Wb = (const float*)d_in[6];
  const float* WP = (const float*)d_in[7];
  float* outp = (float*)d_out;

  char* ws = (char*)d_ws;
  const size_t MB = 1024 * 1024;
  short* Qb   = (short*)(ws + 0);           // 32 MB bf16 Q
  short* Kb   = (short*)(ws + 32 * MB);     // 32 MB bf16 K; reused as WPg later
  short* WQT  = (short*)(ws + 64 * MB);     // 2 MB
  short* WKT  = (short*)(ws + 66 * MB);     // 2 MB
  short* WPT  = (short*)(ws + 68 * MB);     // 2 MB
  float* la   = (float*)(ws + 70 * MB);     // 1 MB (exp of logits, chain 1)
  float* lb   = (float*)(ws + 71 * MB);     // 1 MB (exp of logits, chain 2)
  float* qg   = (float*)(ws + 72 * MB);     // 32 KB
  float* gv   = (float*)(ws + 72 * MB + 64 * 1024); // 32 KB
  short* WaB  = (short*)(ws + 72 * MB + 128 * 1024); // 32 KB bf16 Wa^T
  short* WbB  = (short*)(ws + 72 * MB + 192 * 1024); // 32 KB bf16 Wb^T
  float* part = (float*)(ws + 73 * MB);     // 2 MB
  float* psum = (float*)(ws + 75 * MB);     // 32 KB
  short* WPg  = Kb;                         // Kb dead after pool chain 2

  dim3 tb(256);
  transpose_cvt3<<<dim3(32, 32, 3), tb, 0, stream>>>(WQ, WK, WP, WQT, WKT, WPT);
  w_transpose<<<128, tb, 0, stream>>>(Wa, Wb, WaB, WbB);

  // fused Q/K projections: 256x128 tile, 3-buf counted-vmcnt pipeline
  gemm_pipe<1, 0, 0, 0><<<dim3(8, 64, 2), dim3(512), 0, stream>>>(
      Qseq, Kseq, WQT, WKT, Qb, Kb, nullptr, 1024, 1024);

  skinny_logits<0><<<1024, 64, 0, stream>>>(Qb, WaB, nullptr, la);
  pool_partial<<<512, tb, 0, stream>>>(la, Qb, part, psum);
  pool_reduce<0><<<8, tb, 0, stream>>>(part, psum, nullptr, qg);

  skinny_logits<1><<<1024, 64, 0, stream>>>(Kb, WbB, qg, lb);
  pool_partial<<<512, tb, 0, stream>>>(lb, Kb, part, psum);
  pool_reduce<1><<<8, tb, 0, stream>>>(part, psum, qg, gv);

  // fold gv into WP (per batch), then pure-bf16 out-projection + residual
  wp_scale<<<4096, tb, 0, stream>>>(WPT, gv, WPg);
  gemm_pipe<0, 1, 1, 1><<<dim3(8, 64, 1), dim3(512), 0, stream>>>(
      Qb, Qb, WPg, WPg, outp, outp, Qb, 1024, 1024);
}